// Round 1
// baseline (2508.757 us; speedup 1.0000x reference)
//
#include <hip/hip_runtime.h>
#include <stdint.h>

// ---------------- problem constants ----------------
static constexpr int Hd   = 1024;     // H_DIM
static constexpr int BZn  = 256;      // batch
static constexpr int MTOT = 131072;   // 32 * 4096 keys
static constexpr int BM   = 64;       // key rows per block (main kernel)
static constexpr int NU   = 7;        // units

typedef float  f32x4  __attribute__((ext_vector_type(4)));
typedef short  bf16x8 __attribute__((ext_vector_type(8)));
typedef unsigned short u16;

__device__ __forceinline__ u16 f2bf(float f) {
    unsigned int u = __float_as_uint(f);
    unsigned int r = (u + 0x7FFFu + ((u >> 16) & 1u)) >> 16;  // RNE
    return (u16)r;
}

// ---------------- prep kernels ----------------

// Qrot[256][1024] = query @ R  (f32). 64 blocks x 4 rows.
__global__ void k_qrot(const float* __restrict__ query, const float* __restrict__ R,
                       float* __restrict__ Qrot) {
    __shared__ float qt[4][Hd];
    const int t = threadIdx.x;
    const int r0 = blockIdx.x * 4;
    for (int r = 0; r < 4; ++r)
        *(float4*)(&qt[r][t * 4]) = *(const float4*)(query + (long long)(r0 + r) * Hd + t * 4);
    __syncthreads();
    float acc[4][4] = {};
    for (int k = 0; k < Hd; ++k) {
        float4 rv = *(const float4*)(R + (long long)k * Hd + t * 4);
#pragma unroll
        for (int r = 0; r < 4; ++r) {
            float qv = qt[r][k];
            acc[r][0] += qv * rv.x; acc[r][1] += qv * rv.y;
            acc[r][2] += qv * rv.z; acc[r][3] += qv * rv.w;
        }
    }
    for (int r = 0; r < 4; ++r) {
        float4 o; o.x = acc[r][0]; o.y = acc[r][1]; o.z = acc[r][2]; o.w = acc[r][3];
        *(float4*)(Qrot + (long long)(r0 + r) * Hd + t * 4) = o;
    }
}

// Rpack: B-fragment layout for mfma_f32_16x16x32_bf16.
// frag id = (c0/16)*32 + (k0/32); lane l holds B[k0+(l>>4)*8+j][c0+(l&15)], j=0..7.
// 512 blocks x 256 threads.
__global__ void k_rpack(const float* __restrict__ R, u16* __restrict__ Rpack) {
    const int gt = blockIdx.x * 256 + threadIdx.x;
    const int frag = gt >> 6, lam = gt & 63;
    const int cblk = frag >> 5, kblk = frag & 31;
    const int c  = cblk * 16 + (lam & 15);
    const int k0 = kblk * 32 + (lam >> 4) * 8;
    union { bf16x8 v; u16 u[8]; } p;
#pragma unroll
    for (int j = 0; j < 8; ++j) p.u[j] = f2bf(R[(long long)(k0 + j) * Hd + c]);
    *(bf16x8*)(Rpack + (long long)frag * 512 + lam * 8) = p.v;
}

// Qpack: A-fragment layout. frag id = (c0/32)*16 + (q0/16);
// lane l holds A[q0+(l&15)][c0+(l>>4)*8+j]. 128 blocks x 256 threads.
__global__ void k_qpack(const float* __restrict__ Qrot, u16* __restrict__ Qpack) {
    const int gt = blockIdx.x * 256 + threadIdx.x;
    const int frag = gt >> 6, lam = gt & 63;
    const int cblk = frag >> 4, qblk = frag & 15;
    const int q  = qblk * 16 + (lam & 15);
    const int c0 = cblk * 32 + (lam >> 4) * 8;
    union { bf16x8 v; u16 u[8]; } p;
#pragma unroll
    for (int j = 0; j < 8; ++j) p.u[j] = f2bf(Qrot[(long long)q * Hd + c0 + j]);
    *(bf16x8*)(Qpack + (long long)frag * 512 + lam * 8) = p.v;
}

// ---------------- fused main kernel ----------------
// LDS layout (bytes): keysA[131072] | Bst[16384] | Krot[8192] | rnorm[256]
static constexpr int LDS_KEYS = 0;
static constexpr int LDS_BST  = 131072;
static constexpr int LDS_KROT = 147456;
static constexpr int LDS_RN   = 155648;
static constexpr int LDS_TOT  = 155904;

__global__ __launch_bounds__(256, 1)
void k_main(const float* __restrict__ keys, const u16* __restrict__ Rpack,
            const u16* __restrict__ Qpack, unsigned long long* __restrict__ best) {
    extern __shared__ char smem[];
    char*  keysA = smem + LDS_KEYS;
    char*  Bst   = smem + LDS_BST;
    char*  Krot  = smem + LDS_KROT;
    float* rnorm = (float*)(smem + LDS_RN);

    const int t   = threadIdx.x;
    const int lam = t & 63;
    const int w   = t >> 6;
    const int l15 = lam & 15;
    const int lg  = lam >> 4;
    const long long row0 = (long long)blockIdx.x * BM;

    // ---- stage this block's 64 key rows: f32 -> bf16, swizzled ----
    {
        const float* kb = keys + row0 * Hd;
#pragma unroll 4
        for (int i = 0; i < 32; ++i) {
            int e0 = i * 2048 + t * 8;
            float4 v0 = *(const float4*)(kb + e0);
            float4 v1 = *(const float4*)(kb + e0 + 4);
            int row = e0 >> 10, k = e0 & 1023;
            union { bf16x8 v; u16 u[8]; } p;
            p.u[0] = f2bf(v0.x); p.u[1] = f2bf(v0.y); p.u[2] = f2bf(v0.z); p.u[3] = f2bf(v0.w);
            p.u[4] = f2bf(v1.x); p.u[5] = f2bf(v1.y); p.u[6] = f2bf(v1.z); p.u[7] = f2bf(v1.w);
            int byte = (row * 2048 + k * 2) ^ ((row & 7) << 4);
            *(bf16x8*)(keysA + byte) = p.v;
        }
    }

    f32x4 acc2[4][4];
    float nacc[4];

    for (int ct = 0; ct < 16; ++ct) {
        const bool first = (0xD511 >> ct) & 1;
        const bool last  = (0xEA88 >> ct) & 1;
        const int  u = (ct < 8) ? (ct >> 2) : ((ct < 14) ? (2 + ((ct - 8) >> 1)) : (ct - 9));

        if (first) {
#pragma unroll
            for (int m = 0; m < 4; ++m)
#pragma unroll
                for (int n = 0; n < 4; ++n) acc2[m][n] = (f32x4){0.f, 0.f, 0.f, 0.f};
#pragma unroll
            for (int e = 0; e < 4; ++e) nacc[e] = 0.f;
        }

        // ---- rotation: racc[n] = keys_rows @ R[:, ct*64 + n*16 + ...] ----
        f32x4 racc[4];
#pragma unroll
        for (int n = 0; n < 4; ++n) racc[n] = (f32x4){0.f, 0.f, 0.f, 0.f};

        for (int sr = 0; sr < 8; ++sr) {          // 128 k per stage round
            // stage Bst: 16 fragments (4 ksteps x 4 nfrags), reg-staged
#pragma unroll
            for (int j = 0; j < 4; ++j) {
                int chunk = w * 4 + j;
                int n = chunk & 3, ks4 = chunk >> 2;
                long long src = ((long long)((ct * 4 + n) * 32 + sr * 4 + ks4)) * 512 + lam * 8;
                bf16x8 v = *(const bf16x8*)(Rpack + src);
                *(bf16x8*)(Bst + chunk * 1024 + lam * 16) = v;
            }
            __syncthreads();
#pragma unroll
            for (int ks4 = 0; ks4 < 4; ++ks4) {
                int k0 = sr * 128 + ks4 * 32;
                int arow = w * 16 + l15;
                int abyte = (arow * 2048 + (k0 + lg * 8) * 2) ^ ((arow & 7) << 4);
                bf16x8 a = *(const bf16x8*)(keysA + abyte);
#pragma unroll
                for (int n = 0; n < 4; ++n) {
                    bf16x8 b = *(const bf16x8*)(Bst + (ks4 * 4 + n) * 1024 + lam * 16);
                    racc[n] = __builtin_amdgcn_mfma_f32_16x16x32_bf16(a, b, racc[n], 0, 0, 0);
                }
            }
            __syncthreads();
        }

        // ---- write Krot (bf16, swizzled, UNSCALED) + norm partials ----
#pragma unroll
        for (int n = 0; n < 4; ++n) {
#pragma unroll
            for (int e = 0; e < 4; ++e) {
                int kr = w * 16 + lg * 4 + e;
                int cl = n * 16 + l15;
                int byte = (kr * 128 + cl * 2) ^ ((kr & 7) << 4);
                *(u16*)(Krot + byte) = f2bf(racc[n][e]);
            }
        }
#pragma unroll
        for (int e = 0; e < 4; ++e) {
            float s = racc[0][e] * racc[0][e] + racc[1][e] * racc[1][e] +
                      racc[2][e] * racc[2][e] + racc[3][e] * racc[3][e];
            s += __shfl_xor(s, 1); s += __shfl_xor(s, 2);
            s += __shfl_xor(s, 4); s += __shfl_xor(s, 8);
            nacc[e] += s;
        }
        __syncthreads();

        // ---- sims: acc2[q, kr] += Qrot_sub · Krot^T over this tile's 64 cols ----
#pragma unroll
        for (int cs = 0; cs < 2; ++cs) {
            int c0 = ct * 64 + cs * 32;
            bf16x8 aq[4], bk[4];
#pragma unroll
            for (int m = 0; m < 4; ++m) {
                long long qoff = ((long long)((c0 >> 5) * 16 + (w * 4 + m)) * 64 + lam) * 8;
                aq[m] = *(const bf16x8*)(Qpack + qoff);
            }
#pragma unroll
            for (int n = 0; n < 4; ++n) {
                int kr = n * 16 + l15;
                int byte = (kr * 128 + (cs * 32 + lg * 8) * 2) ^ ((kr & 7) << 4);
                bk[n] = *(const bf16x8*)(Krot + byte);
            }
#pragma unroll
            for (int m = 0; m < 4; ++m)
#pragma unroll
                for (int n = 0; n < 4; ++n)
                    acc2[m][n] = __builtin_amdgcn_mfma_f32_16x16x32_bf16(aq[m], bk[n], acc2[m][n], 0, 0, 0);
        }

        if (last) {
            if (l15 == 0) {
#pragma unroll
                for (int e = 0; e < 4; ++e)
                    rnorm[w * 16 + lg * 4 + e] = 1.0f / fmaxf(sqrtf(nacc[e]), 1e-3f);
            }
            __syncthreads();
            float rn[4];
#pragma unroll
            for (int n = 0; n < 4; ++n) rn[n] = rnorm[n * 16 + l15];
#pragma unroll
            for (int m = 0; m < 4; ++m) {
#pragma unroll
                for (int e = 0; e < 4; ++e) {
                    float bv = acc2[m][0][e] * rn[0];
                    int   bi = 0 * 16 + l15;
#pragma unroll
                    for (int n = 1; n < 4; ++n) {
                        float v = acc2[m][n][e] * rn[n];
                        if (v > bv) { bv = v; bi = n * 16 + l15; }
                    }
#pragma unroll
                    for (int mask = 1; mask <= 8; mask <<= 1) {
                        float ov = __shfl_xor(bv, mask);
                        int   oi = __shfl_xor(bi, mask);
                        if (ov > bv || (ov == bv && oi < bi)) { bv = ov; bi = oi; }
                    }
                    if (l15 == 0) {
                        int q = w * 64 + m * 16 + lg * 4 + e;
                        unsigned int ui = __float_as_uint(bv);
                        unsigned int mp = ui ^ ((ui >> 31) ? 0xFFFFFFFFu : 0x80000000u);
                        unsigned int gl = (unsigned int)row0 + (unsigned int)bi;
                        unsigned long long enc =
                            ((unsigned long long)mp << 32) | (unsigned long long)(0xFFFFFFFFu - gl);
                        atomicMax(best + u * BZn + q, enc);
                    }
                }
            }
            __syncthreads();
        }
    }
}

// ---------------- finish: exact f32 cosine of the winners ----------------
__global__ void k_final(const float* __restrict__ keys, const float* __restrict__ R,
                        const float* __restrict__ Qrot,
                        const unsigned long long* __restrict__ best, float* __restrict__ out) {
    const int fid = blockIdx.x;
    const int u = fid >> 8, b = fid & 255;
    int off, d;
    if (u < 2)      { off = u * 256;            d = 256; }
    else if (u < 5) { off = 512 + (u - 2) * 128; d = 128; }
    else            { off = 896 + (u - 5) * 64;  d = 64;  }

    unsigned long long ent = best[fid];
    if (ent == 0ull) return;  // uniform: no winner -> zero vector -> cos = 0

    __shared__ float krow[Hd];
    __shared__ float red[12];
    const int t = threadIdx.x;
    unsigned int gl = 0xFFFFFFFFu - (unsigned int)(ent & 0xFFFFFFFFull);
    const float* kp = keys + (long long)gl * Hd;
    *(float4*)(&krow[t * 4]) = *(const float4*)(kp + t * 4);
    __syncthreads();

    float pn = 0.f, pq = 0.f, pk = 0.f;
    if (t < d) {
        float kr = 0.f;
        for (int k = 0; k < Hd; ++k) kr += krow[k] * R[(long long)k * Hd + off + t];
        float qv = Qrot[(long long)b * Hd + off + t];
        pn = qv * kr; pq = qv * qv; pk = kr * kr;
    }
    for (int mask = 1; mask <= 32; mask <<= 1) {
        pn += __shfl_xor(pn, mask); pq += __shfl_xor(pq, mask); pk += __shfl_xor(pk, mask);
    }
    if ((t & 63) == 0) { red[t >> 6] = pn; red[4 + (t >> 6)] = pq; red[8 + (t >> 6)] = pk; }
    __syncthreads();
    if (t == 0) {
        float nm = red[0] + red[1] + red[2] + red[3];
        float qq = red[4] + red[5] + red[6] + red[7];
        float kk = red[8] + red[9] + red[10] + red[11];
        float cosv = nm / (fmaxf(sqrtf(qq), 1e-8f) * fmaxf(sqrtf(kk), 1e-8f));
        atomicAdd(out, -cosv * (float)d / (256.0f * 1024.0f));
    }
}

// ---------------- launch ----------------
extern "C" void kernel_launch(void* const* d_in, const int* in_sizes, int n_in,
                              void* d_out, int out_size, void* d_ws, size_t ws_size,
                              hipStream_t stream) {
    (void)in_sizes; (void)n_in; (void)out_size; (void)ws_size;
    const float* query = (const float*)d_in[0];
    const float* keys  = (const float*)d_in[1];
    const float* R     = (const float*)d_in[2];
    float* out = (float*)d_out;
    char* ws = (char*)d_ws;

    unsigned long long* best = (unsigned long long*)ws;        // 14336 B (pad to 16384)
    float* Qrot  = (float*)(ws + 16384);                       // 1 MiB
    u16*   Rpack = (u16*)(ws + 16384 + 1048576);               // 2 MiB
    u16*   Qpack = (u16*)(ws + 16384 + 1048576 + 2097152);     // 512 KiB

    hipMemsetAsync(best, 0, NU * BZn * sizeof(unsigned long long), stream);
    hipMemsetAsync(out, 0, sizeof(float), stream);

    k_qrot <<<64,  256, 0, stream>>>(query, R, Qrot);
    k_rpack<<<512, 256, 0, stream>>>(R, Rpack);
    k_qpack<<<128, 256, 0, stream>>>(Qrot, Qpack);

    hipFuncSetAttribute((const void*)k_main,
                        hipFuncAttributeMaxDynamicSharedMemorySize, LDS_TOT);
    k_main <<<MTOT / BM, 256, LDS_TOT, stream>>>(keys, Rpack, Qpack, best);
    k_final<<<NU * BZn, 256, 0, stream>>>(keys, R, Qrot, best, out);
}

// Round 2
// 1224.822 us; speedup vs baseline: 2.0483x; 2.0483x over previous
//
#include <hip/hip_runtime.h>
#include <stdint.h>

// ---------------- problem constants ----------------
static constexpr int Hd   = 1024;     // H_DIM
static constexpr int BZn  = 256;      // batch
static constexpr int MTOT = 131072;   // 32 * 4096 keys
static constexpr int BM   = 64;       // key rows per block (main kernel)
static constexpr int NU   = 7;        // units

typedef float  f32x4  __attribute__((ext_vector_type(4)));
typedef short  bf16x8 __attribute__((ext_vector_type(8)));
typedef unsigned short u16;

__device__ __forceinline__ u16 f2bf(float f) {
    unsigned int u = __float_as_uint(f);
    unsigned int r = (u + 0x7FFFu + ((u >> 16) & 1u)) >> 16;  // RNE
    return (u16)r;
}

// ---------------- prep kernels ----------------

// Qrot[256][1024] = query @ R  (f32). 64 blocks x 4 rows.
__global__ void k_qrot(const float* __restrict__ query, const float* __restrict__ R,
                       float* __restrict__ Qrot) {
    __shared__ float qt[4][Hd];
    const int t = threadIdx.x;
    const int r0 = blockIdx.x * 4;
    for (int r = 0; r < 4; ++r)
        *(float4*)(&qt[r][t * 4]) = *(const float4*)(query + (long long)(r0 + r) * Hd + t * 4);
    __syncthreads();
    float acc[4][4] = {};
    for (int k = 0; k < Hd; ++k) {
        float4 rv = *(const float4*)(R + (long long)k * Hd + t * 4);
#pragma unroll
        for (int r = 0; r < 4; ++r) {
            float qv = qt[r][k];
            acc[r][0] += qv * rv.x; acc[r][1] += qv * rv.y;
            acc[r][2] += qv * rv.z; acc[r][3] += qv * rv.w;
        }
    }
    for (int r = 0; r < 4; ++r) {
        float4 o; o.x = acc[r][0]; o.y = acc[r][1]; o.z = acc[r][2]; o.w = acc[r][3];
        *(float4*)(Qrot + (long long)(r0 + r) * Hd + t * 4) = o;
    }
}

// Rpack: B-fragment layout for mfma_f32_16x16x32_bf16.
// frag id = (c0/16)*32 + (k0/32); lane l holds B[k0+(l>>4)*8+j][c0+(l&15)], j=0..7.
__global__ void k_rpack(const float* __restrict__ R, u16* __restrict__ Rpack) {
    const int gt = blockIdx.x * 256 + threadIdx.x;
    const int frag = gt >> 6, lam = gt & 63;
    const int cblk = frag >> 5, kblk = frag & 31;
    const int c  = cblk * 16 + (lam & 15);
    const int k0 = kblk * 32 + (lam >> 4) * 8;
    union { bf16x8 v; u16 u[8]; } p;
#pragma unroll
    for (int j = 0; j < 8; ++j) p.u[j] = f2bf(R[(long long)(k0 + j) * Hd + c]);
    *(bf16x8*)(Rpack + (long long)frag * 512 + lam * 8) = p.v;
}

// Qpack: A-fragment layout. frag id = (c0/32)*16 + (q0/16);
// lane l holds A[q0+(l&15)][c0+(l>>4)*8+j].
__global__ void k_qpack(const float* __restrict__ Qrot, u16* __restrict__ Qpack) {
    const int gt = blockIdx.x * 256 + threadIdx.x;
    const int frag = gt >> 6, lam = gt & 63;
    const int cblk = frag >> 4, qblk = frag & 15;
    const int q  = qblk * 16 + (lam & 15);
    const int c0 = cblk * 32 + (lam >> 4) * 8;
    union { bf16x8 v; u16 u[8]; } p;
#pragma unroll
    for (int j = 0; j < 8; ++j) p.u[j] = f2bf(Qrot[(long long)q * Hd + c0 + j]);
    *(bf16x8*)(Qpack + (long long)frag * 512 + lam * 8) = p.v;
}

// ---------------- fused main kernel (512 threads = 8 waves) ----------------
// LDS layout (bytes): keysA[131072] | Bst[16384] | Krot[8192] | rnormP[512]
static constexpr int LDS_KEYS = 0;
static constexpr int LDS_BST  = 131072;
static constexpr int LDS_KROT = 147456;
static constexpr int LDS_RN   = 155648;
static constexpr int LDS_TOT  = 156160;

__global__ __launch_bounds__(512, 1)
void k_main(const float* __restrict__ keys, const u16* __restrict__ Rpack,
            const u16* __restrict__ Qpack, unsigned long long* __restrict__ best) {
    extern __shared__ char smem[];
    char*  keysA  = smem + LDS_KEYS;
    char*  Bst    = smem + LDS_BST;
    char*  Krot   = smem + LDS_KROT;
    float* rnormP = (float*)(smem + LDS_RN);   // [2][64] partial sq-norms

    const int t   = threadIdx.x;
    const int lam = t & 63;
    const int w   = t >> 6;          // 8 waves
    const int l15 = lam & 15;
    const int lg  = lam >> 4;
    const int wr  = w & 3;           // row-group (16 rows)
    const int wc  = w >> 2;          // col-group (32 cols)
    const long long row0 = (long long)blockIdx.x * BM;

    // ---- stage this block's 64 key rows: f32 -> bf16, swizzled ----
    {
        const float* kb = keys + row0 * Hd;
#pragma unroll 4
        for (int i = 0; i < 16; ++i) {
            int e0 = i * 4096 + t * 8;
            float4 v0 = *(const float4*)(kb + e0);
            float4 v1 = *(const float4*)(kb + e0 + 4);
            int row = e0 >> 10, k = e0 & 1023;
            union { bf16x8 v; u16 u[8]; } p;
            p.u[0] = f2bf(v0.x); p.u[1] = f2bf(v0.y); p.u[2] = f2bf(v0.z); p.u[3] = f2bf(v0.w);
            p.u[4] = f2bf(v1.x); p.u[5] = f2bf(v1.y); p.u[6] = f2bf(v1.z); p.u[7] = f2bf(v1.w);
            int byte = (row * 2048 + k * 2) ^ ((row & 7) << 4);
            *(bf16x8*)(keysA + byte) = p.v;
        }
    }

    // Per-thread Bst staging geometry: 16 frags x 64 lanes = 1024 units; 2 per thread.
    const int fl0 = t >> 6;                 // frag 0..7   (i = 0)
    const int fl1 = (t >> 6) + 8;           // frag 8..15  (i = 1)
    const int sl  = t & 63;                 // staging lane
    const int dst0 = fl0 * 1024 + sl * 16;
    const int dst1 = fl1 * 1024 + sl * 16;

    auto pf_src = [&](int g, int fl) -> long long {
        int ct2 = g >> 3, sr2 = g & 7;
        int n = fl & 3, ks4 = fl >> 2;
        return ((long long)((ct2 * 4 + n) * 32 + sr2 * 4 + ks4)) * 512 + sl * 8;
    };

    // prologue prefetch for round g=0
    bf16x8 pf0 = *(const bf16x8*)(Rpack + pf_src(0, fl0));
    bf16x8 pf1 = *(const bf16x8*)(Rpack + pf_src(0, fl1));

    f32x4 acc2[2][4];
    float nacc[4];

    for (int ct = 0; ct < 16; ++ct) {
        const bool first = (0xD511 >> ct) & 1;
        const bool last  = (0xEA88 >> ct) & 1;
        const int  u = (ct < 8) ? (ct >> 2) : ((ct < 14) ? (2 + ((ct - 8) >> 1)) : (ct - 9));

        if (first) {
#pragma unroll
            for (int m = 0; m < 2; ++m)
#pragma unroll
                for (int n = 0; n < 4; ++n) acc2[m][n] = (f32x4){0.f, 0.f, 0.f, 0.f};
#pragma unroll
            for (int e = 0; e < 4; ++e) nacc[e] = 0.f;
        }

        // ---- rotation: racc[n2] = keys_rows @ R[:, ct*64 + (wc*2+n2)*16 + ...] ----
        f32x4 racc[2];
#pragma unroll
        for (int n = 0; n < 2; ++n) racc[n] = (f32x4){0.f, 0.f, 0.f, 0.f};

        for (int sr = 0; sr < 8; ++sr) {          // 128 k per stage round
            __syncthreads();                       // Bst free (prev round consumed)
            *(bf16x8*)(Bst + dst0) = pf0;          // write staged B (waits vmcnt)
            *(bf16x8*)(Bst + dst1) = pf1;
            int g2 = (ct * 8 + sr + 1) & 127;      // prefetch next round
            pf0 = *(const bf16x8*)(Rpack + pf_src(g2, fl0));
            pf1 = *(const bf16x8*)(Rpack + pf_src(g2, fl1));
            __syncthreads();                       // Bst visible
#pragma unroll
            for (int ks4 = 0; ks4 < 4; ++ks4) {
                int kk = sr * 128 + ks4 * 32 + lg * 8;
                int arow = wr * 16 + l15;
                int abyte = (arow * 2048 + kk * 2) ^ ((arow & 7) << 4);
                bf16x8 a = *(const bf16x8*)(keysA + abyte);
#pragma unroll
                for (int n2 = 0; n2 < 2; ++n2) {
                    int nf = wc * 2 + n2;
                    bf16x8 b = *(const bf16x8*)(Bst + (ks4 * 4 + nf) * 1024 + lam * 16);
                    racc[n2] = __builtin_amdgcn_mfma_f32_16x16x32_bf16(a, b, racc[n2], 0, 0, 0);
                }
            }
        }

        // ---- write Krot (bf16, swizzled, UNSCALED) + norm partials ----
#pragma unroll
        for (int n2 = 0; n2 < 2; ++n2) {
            int cl = (wc * 2 + n2) * 16 + l15;
#pragma unroll
            for (int e = 0; e < 4; ++e) {
                int kr = wr * 16 + lg * 4 + e;
                int byte = (kr * 128 + cl * 2) ^ ((kr & 7) << 4);
                *(u16*)(Krot + byte) = f2bf(racc[n2][e]);
            }
        }
#pragma unroll
        for (int e = 0; e < 4; ++e) {
            float s = racc[0][e] * racc[0][e] + racc[1][e] * racc[1][e];
            s += __shfl_xor(s, 1); s += __shfl_xor(s, 2);
            s += __shfl_xor(s, 4); s += __shfl_xor(s, 8);
            nacc[e] += s;
        }
        if (last && l15 == 0) {
#pragma unroll
            for (int e = 0; e < 4; ++e)
                rnormP[wc * 64 + wr * 16 + lg * 4 + e] = nacc[e];
        }
        __syncthreads();   // Krot + rnormP visible

        // ---- sims: acc2[q, kr] += Qrot_sub · Krot^T over this tile's 64 cols ----
#pragma unroll
        for (int cs = 0; cs < 2; ++cs) {
            int c0 = ct * 64 + cs * 32;
            bf16x8 aq[2], bk[4];
#pragma unroll
            for (int m = 0; m < 2; ++m) {
                long long qoff = ((long long)((c0 >> 5) * 16 + (w * 2 + m)) * 64 + lam) * 8;
                aq[m] = *(const bf16x8*)(Qpack + qoff);
            }
#pragma unroll
            for (int n = 0; n < 4; ++n) {
                int kr = n * 16 + l15;
                int byte = (kr * 128 + (cs * 32 + lg * 8) * 2) ^ ((kr & 7) << 4);
                bk[n] = *(const bf16x8*)(Krot + byte);
            }
#pragma unroll
            for (int m = 0; m < 2; ++m)
#pragma unroll
                for (int n = 0; n < 4; ++n)
                    acc2[m][n] = __builtin_amdgcn_mfma_f32_16x16x32_bf16(aq[m], bk[n], acc2[m][n], 0, 0, 0);
        }

        if (last) {
            float rn[4];
#pragma unroll
            for (int n = 0; n < 4; ++n) {
                float p = rnormP[n * 16 + l15] + rnormP[64 + n * 16 + l15];
                rn[n] = 1.0f / fmaxf(sqrtf(p), 1e-3f);
            }
#pragma unroll
            for (int m = 0; m < 2; ++m) {
#pragma unroll
                for (int e = 0; e < 4; ++e) {
                    float bv = acc2[m][0][e] * rn[0];
                    int   bi = l15;
#pragma unroll
                    for (int n = 1; n < 4; ++n) {
                        float v = acc2[m][n][e] * rn[n];
                        if (v > bv) { bv = v; bi = n * 16 + l15; }
                    }
#pragma unroll
                    for (int mask = 1; mask <= 8; mask <<= 1) {
                        float ov = __shfl_xor(bv, mask);
                        int   oi = __shfl_xor(bi, mask);
                        if (ov > bv || (ov == bv && oi < bi)) { bv = ov; bi = oi; }
                    }
                    if (l15 == 0) {
                        int q = (w * 2 + m) * 16 + lg * 4 + e;
                        unsigned int ui = __float_as_uint(bv);
                        unsigned int mp = ui ^ ((ui >> 31) ? 0xFFFFFFFFu : 0x80000000u);
                        unsigned int gl = (unsigned int)row0 + (unsigned int)bi;
                        unsigned long long enc =
                            ((unsigned long long)mp << 32) | (unsigned long long)(0xFFFFFFFFu - gl);
                        atomicMax(best + u * BZn + q, enc);
                    }
                }
            }
        }
        // next iteration's first __syncthreads() separates Krot readers from writers
    }
}

// ---------------- finish: exact f32 cosine of the winners ----------------
__global__ void k_final(const float* __restrict__ keys, const float* __restrict__ R,
                        const float* __restrict__ Qrot,
                        const unsigned long long* __restrict__ best, float* __restrict__ out) {
    const int fid = blockIdx.x;
    const int u = fid >> 8, b = fid & 255;
    int off, d;
    if (u < 2)      { off = u * 256;            d = 256; }
    else if (u < 5) { off = 512 + (u - 2) * 128; d = 128; }
    else            { off = 896 + (u - 5) * 64;  d = 64;  }

    unsigned long long ent = best[fid];
    if (ent == 0ull) return;  // no winner -> zero vector -> cos = 0

    __shared__ float krow[Hd];
    __shared__ float red[12];
    const int t = threadIdx.x;
    unsigned int gl = 0xFFFFFFFFu - (unsigned int)(ent & 0xFFFFFFFFull);
    const float* kp = keys + (long long)gl * Hd;
    *(float4*)(&krow[t * 4]) = *(const float4*)(kp + t * 4);
    __syncthreads();

    float pn = 0.f, pq = 0.f, pk = 0.f;
    if (t < d) {
        float kr = 0.f;
        for (int k = 0; k < Hd; ++k) kr += krow[k] * R[(long long)k * Hd + off + t];
        float qv = Qrot[(long long)b * Hd + off + t];
        pn = qv * kr; pq = qv * qv; pk = kr * kr;
    }
    for (int mask = 1; mask <= 32; mask <<= 1) {
        pn += __shfl_xor(pn, mask); pq += __shfl_xor(pq, mask); pk += __shfl_xor(pk, mask);
    }
    if ((t & 63) == 0) { red[t >> 6] = pn; red[4 + (t >> 6)] = pq; red[8 + (t >> 6)] = pk; }
    __syncthreads();
    if (t == 0) {
        float nm = red[0] + red[1] + red[2] + red[3];
        float qq = red[4] + red[5] + red[6] + red[7];
        float kk = red[8] + red[9] + red[10] + red[11];
        float cosv = nm / (fmaxf(sqrtf(qq), 1e-8f) * fmaxf(sqrtf(kk), 1e-8f));
        atomicAdd(out, -cosv * (float)d / (256.0f * 1024.0f));
    }
}

// ---------------- launch ----------------
extern "C" void kernel_launch(void* const* d_in, const int* in_sizes, int n_in,
                              void* d_out, int out_size, void* d_ws, size_t ws_size,
                              hipStream_t stream) {
    (void)in_sizes; (void)n_in; (void)out_size; (void)ws_size;
    const float* query = (const float*)d_in[0];
    const float* keys  = (const float*)d_in[1];
    const float* R     = (const float*)d_in[2];
    float* out = (float*)d_out;
    char* ws = (char*)d_ws;

    unsigned long long* best = (unsigned long long*)ws;        // 14336 B (pad to 16384)
    float* Qrot  = (float*)(ws + 16384);                       // 1 MiB
    u16*   Rpack = (u16*)(ws + 16384 + 1048576);               // 2 MiB
    u16*   Qpack = (u16*)(ws + 16384 + 1048576 + 2097152);     // 512 KiB

    hipMemsetAsync(best, 0, NU * BZn * sizeof(unsigned long long), stream);
    hipMemsetAsync(out, 0, sizeof(float), stream);

    k_qrot <<<64,  256, 0, stream>>>(query, R, Qrot);
    k_rpack<<<512, 256, 0, stream>>>(R, Rpack);
    k_qpack<<<128, 256, 0, stream>>>(Qrot, Qpack);

    hipFuncSetAttribute((const void*)k_main,
                        hipFuncAttributeMaxDynamicSharedMemorySize, LDS_TOT);
    k_main <<<MTOT / BM, 512, LDS_TOT, stream>>>(keys, Rpack, Qpack, best);
    k_final<<<NU * BZn, 256, 0, stream>>>(keys, R, Qrot, best, out);
}

// Round 3
// 1127.723 us; speedup vs baseline: 2.2246x; 1.0861x over previous
//
#include <hip/hip_runtime.h>
#include <stdint.h>

// ---------------- problem constants ----------------
static constexpr int Hd   = 1024;     // H_DIM
static constexpr int BZn  = 256;      // batch
static constexpr int MTOT = 131072;   // 32 * 4096 keys
static constexpr int BM   = 64;       // key rows per block (main kernel)
static constexpr int NU   = 7;        // units

typedef float  f32x4  __attribute__((ext_vector_type(4)));
typedef short  bf16x8 __attribute__((ext_vector_type(8)));
typedef unsigned short u16;

__device__ __forceinline__ u16 f2bf(float f) {
    unsigned int u = __float_as_uint(f);
    unsigned int r = (u + 0x7FFFu + ((u >> 16) & 1u)) >> 16;  // RNE
    return (u16)r;
}

// ---------------- prep kernels ----------------

// Qrot[256][1024] = query @ R  (f32). 64 blocks x 4 rows.
__global__ void k_qrot(const float* __restrict__ query, const float* __restrict__ R,
                       float* __restrict__ Qrot) {
    __shared__ float qt[4][Hd];
    const int t = threadIdx.x;
    const int r0 = blockIdx.x * 4;
    for (int r = 0; r < 4; ++r)
        *(float4*)(&qt[r][t * 4]) = *(const float4*)(query + (long long)(r0 + r) * Hd + t * 4);
    __syncthreads();
    float acc[4][4] = {};
    for (int k = 0; k < Hd; ++k) {
        float4 rv = *(const float4*)(R + (long long)k * Hd + t * 4);
#pragma unroll
        for (int r = 0; r < 4; ++r) {
            float qv = qt[r][k];
            acc[r][0] += qv * rv.x; acc[r][1] += qv * rv.y;
            acc[r][2] += qv * rv.z; acc[r][3] += qv * rv.w;
        }
    }
    for (int r = 0; r < 4; ++r) {
        float4 o; o.x = acc[r][0]; o.y = acc[r][1]; o.z = acc[r][2]; o.w = acc[r][3];
        *(float4*)(Qrot + (long long)(r0 + r) * Hd + t * 4) = o;
    }
}

// Rpack: B-fragment layout for mfma_f32_16x16x32_bf16.
// frag id = (c0/16)*32 + (k0/32); lane l holds B[k0+(l>>4)*8+j][c0+(l&15)], j=0..7.
__global__ void k_rpack(const float* __restrict__ R, u16* __restrict__ Rpack) {
    const int gt = blockIdx.x * 256 + threadIdx.x;
    const int frag = gt >> 6, lam = gt & 63;
    const int cblk = frag >> 5, kblk = frag & 31;
    const int c  = cblk * 16 + (lam & 15);
    const int k0 = kblk * 32 + (lam >> 4) * 8;
    union { bf16x8 v; u16 u[8]; } p;
#pragma unroll
    for (int j = 0; j < 8; ++j) p.u[j] = f2bf(R[(long long)(k0 + j) * Hd + c]);
    *(bf16x8*)(Rpack + (long long)frag * 512 + lam * 8) = p.v;
}

// Qpack: A-fragment layout. frag id = (c0/32)*16 + (q0/16);
// lane l holds A[q0+(l&15)][c0+(l>>4)*8+j].
__global__ void k_qpack(const float* __restrict__ Qrot, u16* __restrict__ Qpack) {
    const int gt = blockIdx.x * 256 + threadIdx.x;
    const int frag = gt >> 6, lam = gt & 63;
    const int cblk = frag >> 4, qblk = frag & 15;
    const int q  = qblk * 16 + (lam & 15);
    const int c0 = cblk * 32 + (lam >> 4) * 8;
    union { bf16x8 v; u16 u[8]; } p;
#pragma unroll
    for (int j = 0; j < 8; ++j) p.u[j] = f2bf(Qrot[(long long)q * Hd + c0 + j]);
    *(bf16x8*)(Qpack + (long long)frag * 512 + lam * 8) = p.v;
}

// ---------------- fused main kernel (512 threads = 8 waves) ----------------
// LDS layout (bytes): keysA[131072] | Krot[2][8192] | rnormP[512]
static constexpr int LDS_KEYS = 0;
static constexpr int LDS_KROT = 131072;
static constexpr int LDS_RN   = 147456;
static constexpr int LDS_TOT  = 147968;

__global__ __launch_bounds__(512, 1)
void k_main(const float* __restrict__ keys, const u16* __restrict__ Rpack,
            const u16* __restrict__ Qpack, unsigned long long* __restrict__ best) {
    extern __shared__ char smem[];
    char*  keysA  = smem + LDS_KEYS;
    float* rnormP = (float*)(smem + LDS_RN);   // [2][64] partial sq-norms

    const int t   = threadIdx.x;
    const int lam = t & 63;
    const int w   = t >> 6;          // 8 waves
    const int l15 = lam & 15;
    const int lg  = lam >> 4;
    const int wr  = w & 3;           // row-group (16 rows)
    const int wc  = w >> 2;          // col-group (32 cols)
    const long long row0 = (long long)blockIdx.x * BM;

    // ---- stage this block's 64 key rows: f32 -> bf16, swizzled ----
    {
        const float* kb = keys + row0 * Hd;
#pragma unroll 4
        for (int i = 0; i < 16; ++i) {
            int e0 = i * 4096 + t * 8;
            float4 v0 = *(const float4*)(kb + e0);
            float4 v1 = *(const float4*)(kb + e0 + 4);
            int row = e0 >> 10, k = e0 & 1023;
            union { bf16x8 v; u16 u[8]; } p;
            p.u[0] = f2bf(v0.x); p.u[1] = f2bf(v0.y); p.u[2] = f2bf(v0.z); p.u[3] = f2bf(v0.w);
            p.u[4] = f2bf(v1.x); p.u[5] = f2bf(v1.y); p.u[6] = f2bf(v1.z); p.u[7] = f2bf(v1.w);
            int byte = (row * 2048 + k * 2) ^ ((row & 7) << 4);
            *(bf16x8*)(keysA + byte) = p.v;
        }
    }
    __syncthreads();

    // B-frag byte address in Rpack for this lane: frag = (ct*4+nf)*32 + step
    auto bsrc = [&](int ct2, int nf, int step) -> long long {
        return ((long long)((ct2 * 4 + nf) * 32 + step)) * 1024 + lam * 16;
    };
    const char* RpB = (const char*)Rpack;

    f32x4 acc2[2][4];
    float nacc[4];

    for (int ct = 0; ct < 16; ++ct) {
        const bool first = (0xD511 >> ct) & 1;
        const bool last  = (0xEA88 >> ct) & 1;
        const int  u = (ct < 8) ? (ct >> 2) : ((ct < 14) ? (2 + ((ct - 8) >> 1)) : (ct - 9));
        const int  buf = ct & 1;
        char* Krot = smem + LDS_KROT + buf * 8192;

        if (first) {
#pragma unroll
            for (int m = 0; m < 2; ++m)
#pragma unroll
                for (int n = 0; n < 4; ++n) acc2[m][n] = (f32x4){0.f, 0.f, 0.f, 0.f};
#pragma unroll
            for (int e = 0; e < 4; ++e) nacc[e] = 0.f;
        }

        // ---- prefetch sims A-frags (Qpack, L2) — consumed after the barrier ----
        bf16x8 aq[2][2];
#pragma unroll
        for (int cs = 0; cs < 2; ++cs)
#pragma unroll
            for (int m = 0; m < 2; ++m) {
                long long qoff = ((long long)((ct * 2 + cs) * 16 + (w * 2 + m)) * 64 + lam) * 8;
                aq[cs][m] = *(const bf16x8*)(Qpack + qoff);
            }

        // ---- rotation: racc[n2] = keys_rows @ R[:, ct*64 + (wc*2+n2)*16 + ...] ----
        // B-frags streamed straight from L2 (Rpack), 1-round software prefetch,
        // ZERO barriers in this loop.
        f32x4 racc[2];
        racc[0] = (f32x4){0.f, 0.f, 0.f, 0.f};
        racc[1] = (f32x4){0.f, 0.f, 0.f, 0.f};

        bf16x8 nb0[4], nb1[4];
#pragma unroll
        for (int k4 = 0; k4 < 4; ++k4) {
            nb0[k4] = *(const bf16x8*)(RpB + bsrc(ct, wc * 2 + 0, k4));
            nb1[k4] = *(const bf16x8*)(RpB + bsrc(ct, wc * 2 + 1, k4));
        }
        const int arow  = wr * 16 + l15;
        const int aswz  = (arow & 7) << 4;
        const int abase = arow * 2048 + lg * 16;

        for (int sr = 0; sr < 8; ++sr) {
            bf16x8 cb0[4], cb1[4];
#pragma unroll
            for (int k4 = 0; k4 < 4; ++k4) { cb0[k4] = nb0[k4]; cb1[k4] = nb1[k4]; }
            if (sr < 7) {
#pragma unroll
                for (int k4 = 0; k4 < 4; ++k4) {
                    int step = (sr + 1) * 4 + k4;
                    nb0[k4] = *(const bf16x8*)(RpB + bsrc(ct, wc * 2 + 0, step));
                    nb1[k4] = *(const bf16x8*)(RpB + bsrc(ct, wc * 2 + 1, step));
                }
            }
#pragma unroll
            for (int k4 = 0; k4 < 4; ++k4) {
                int abyte = (abase + (sr * 4 + k4) * 64) ^ aswz;
                bf16x8 a = *(const bf16x8*)(keysA + abyte);
                racc[0] = __builtin_amdgcn_mfma_f32_16x16x32_bf16(a, cb0[k4], racc[0], 0, 0, 0);
                racc[1] = __builtin_amdgcn_mfma_f32_16x16x32_bf16(a, cb1[k4], racc[1], 0, 0, 0);
            }
        }

        // ---- write Krot (bf16, swizzled, UNSCALED) + norm partials ----
#pragma unroll
        for (int n2 = 0; n2 < 2; ++n2) {
            int cl = (wc * 2 + n2) * 16 + l15;
#pragma unroll
            for (int e = 0; e < 4; ++e) {
                int kr = wr * 16 + lg * 4 + e;
                int byte = (kr * 128 + cl * 2) ^ ((kr & 7) << 4);
                *(u16*)(Krot + byte) = f2bf(racc[n2][e]);
            }
        }
#pragma unroll
        for (int e = 0; e < 4; ++e) {
            float s = racc[0][e] * racc[0][e] + racc[1][e] * racc[1][e];
            s += __shfl_xor(s, 1); s += __shfl_xor(s, 2);
            s += __shfl_xor(s, 4); s += __shfl_xor(s, 8);
            nacc[e] += s;
        }
        if (last && l15 == 0) {
#pragma unroll
            for (int e = 0; e < 4; ++e)
                rnormP[wc * 64 + wr * 16 + lg * 4 + e] = nacc[e];
        }
        __syncthreads();   // the ONLY barrier per ct: Krot + rnormP visible

        // ---- sims: acc2[q, kr] += Qrot_sub · Krot^T over this tile's 64 cols ----
#pragma unroll
        for (int cs = 0; cs < 2; ++cs) {
            bf16x8 bk[4];
#pragma unroll
            for (int n = 0; n < 4; ++n) {
                int kr = n * 16 + l15;
                int byte = (kr * 128 + (cs * 32 + lg * 8) * 2) ^ ((kr & 7) << 4);
                bk[n] = *(const bf16x8*)(Krot + byte);
            }
#pragma unroll
            for (int m = 0; m < 2; ++m)
#pragma unroll
                for (int n = 0; n < 4; ++n)
                    acc2[m][n] = __builtin_amdgcn_mfma_f32_16x16x32_bf16(aq[cs][m], bk[n], acc2[m][n], 0, 0, 0);
        }

        if (last) {
            float rn[4];
#pragma unroll
            for (int n = 0; n < 4; ++n) {
                float p = rnormP[n * 16 + l15] + rnormP[64 + n * 16 + l15];
                rn[n] = 1.0f / fmaxf(sqrtf(p), 1e-3f);
            }
#pragma unroll
            for (int m = 0; m < 2; ++m) {
#pragma unroll
                for (int e = 0; e < 4; ++e) {
                    float bv = acc2[m][0][e] * rn[0];
                    int   bi = l15;
#pragma unroll
                    for (int n = 1; n < 4; ++n) {
                        float v = acc2[m][n][e] * rn[n];
                        if (v > bv) { bv = v; bi = n * 16 + l15; }
                    }
#pragma unroll
                    for (int mask = 1; mask <= 8; mask <<= 1) {
                        float ov = __shfl_xor(bv, mask);
                        int   oi = __shfl_xor(bi, mask);
                        if (ov > bv || (ov == bv && oi < bi)) { bv = ov; bi = oi; }
                    }
                    if (l15 == 0) {
                        int q = (w * 2 + m) * 16 + lg * 4 + e;
                        unsigned int ui = __float_as_uint(bv);
                        unsigned int mp = ui ^ ((ui >> 31) ? 0xFFFFFFFFu : 0x80000000u);
                        unsigned int gl = (unsigned int)row0 + (unsigned int)bi;
                        unsigned long long enc =
                            ((unsigned long long)mp << 32) | (unsigned long long)(0xFFFFFFFFu - gl);
                        atomicMax(best + u * BZn + q, enc);
                    }
                }
            }
        }
        // Krot is double-buffered: next ct writes buf^1, so no trailing barrier.
    }
}

// ---------------- finish: exact f32 cosine of the winners ----------------
__global__ void k_final(const float* __restrict__ keys, const float* __restrict__ R,
                        const float* __restrict__ Qrot,
                        const unsigned long long* __restrict__ best, float* __restrict__ out) {
    const int fid = blockIdx.x;
    const int u = fid >> 8, b = fid & 255;
    int off, d;
    if (u < 2)      { off = u * 256;            d = 256; }
    else if (u < 5) { off = 512 + (u - 2) * 128; d = 128; }
    else            { off = 896 + (u - 5) * 64;  d = 64;  }

    unsigned long long ent = best[fid];
    if (ent == 0ull) return;  // no winner -> zero vector -> cos = 0

    __shared__ float krow[Hd];
    __shared__ float red[12];
    const int t = threadIdx.x;
    unsigned int gl = 0xFFFFFFFFu - (unsigned int)(ent & 0xFFFFFFFFull);
    const float* kp = keys + (long long)gl * Hd;
    *(float4*)(&krow[t * 4]) = *(const float4*)(kp + t * 4);
    __syncthreads();

    float pn = 0.f, pq = 0.f, pk = 0.f;
    if (t < d) {
        float kr = 0.f;
        for (int k = 0; k < Hd; ++k) kr += krow[k] * R[(long long)k * Hd + off + t];
        float qv = Qrot[(long long)b * Hd + off + t];
        pn = qv * kr; pq = qv * qv; pk = kr * kr;
    }
    for (int mask = 1; mask <= 32; mask <<= 1) {
        pn += __shfl_xor(pn, mask); pq += __shfl_xor(pq, mask); pk += __shfl_xor(pk, mask);
    }
    if ((t & 63) == 0) { red[t >> 6] = pn; red[4 + (t >> 6)] = pq; red[8 + (t >> 6)] = pk; }
    __syncthreads();
    if (t == 0) {
        float nm = red[0] + red[1] + red[2] + red[3];
        float qq = red[4] + red[5] + red[6] + red[7];
        float kk = red[8] + red[9] + red[10] + red[11];
        float cosv = nm / (fmaxf(sqrtf(qq), 1e-8f) * fmaxf(sqrtf(kk), 1e-8f));
        atomicAdd(out, -cosv * (float)d / (256.0f * 1024.0f));
    }
}

// ---------------- launch ----------------
extern "C" void kernel_launch(void* const* d_in, const int* in_sizes, int n_in,
                              void* d_out, int out_size, void* d_ws, size_t ws_size,
                              hipStream_t stream) {
    (void)in_sizes; (void)n_in; (void)out_size; (void)ws_size;
    const float* query = (const float*)d_in[0];
    const float* keys  = (const float*)d_in[1];
    const float* R     = (const float*)d_in[2];
    float* out = (float*)d_out;
    char* ws = (char*)d_ws;

    unsigned long long* best = (unsigned long long*)ws;        // 14336 B (pad to 16384)
    float* Qrot  = (float*)(ws + 16384);                       // 1 MiB
    u16*   Rpack = (u16*)(ws + 16384 + 1048576);               // 2 MiB
    u16*   Qpack = (u16*)(ws + 16384 + 1048576 + 2097152);     // 512 KiB

    hipMemsetAsync(best, 0, NU * BZn * sizeof(unsigned long long), stream);
    hipMemsetAsync(out, 0, sizeof(float), stream);

    k_qrot <<<64,  256, 0, stream>>>(query, R, Qrot);
    k_rpack<<<512, 256, 0, stream>>>(R, Rpack);
    k_qpack<<<128, 256, 0, stream>>>(Qrot, Qpack);

    hipFuncSetAttribute((const void*)k_main,
                        hipFuncAttributeMaxDynamicSharedMemorySize, LDS_TOT);
    k_main <<<MTOT / BM, 512, LDS_TOT, stream>>>(keys, Rpack, Qpack, best);
    k_final<<<NU * BZn, 256, 0, stream>>>(keys, R, Qrot, best, out);
}